// Round 21
// baseline (241.752 us; speedup 1.0000x reference)
//
#include <hip/hip_runtime.h>
#include <math.h>

// SSIM loss. R21: BARRIER-FREE wave-private tiles + column pairing.
// Wave owns 128 output cols (64 lanes x 2 cols); halo (10 cols, +8% work)
// loaded redundantly by lanes 0-4 / 59-63. Zero block barriers anywhere:
// intra-wave LDS visibility via lgkmcnt(0) (R14-proven) -> 2048 fully
// independent wave streams. R20 analysis: NT 512->256 halved waves to
// 2/SIMD *convoyed*; per-SIMD VALU ~10us + LDS ~12us << measured 36us ->
// latency-exposed. Decouple streams instead of adding waves.
//  - 4 fields {p,g,s=p^2+g^2,c=p*g} f16-packed, parity-split entries
//  - 24 ds_read_b128/group (12 per output col), static weights
//  - fully-static group instantiation, 16-slot rings, fdot2 scatter pruned
// Falsified: barrier-drain(R15), more blocks(R8/R17), super-groups(R18).
// Spill ledger: static indices, minimal prefetch state, generous budget.

#define KW 11
#define HALF 5
#define STRIP 32
#define W 512
#define H 512
#define NT 256

static constexpr float kC1 = 0.0001f;
static constexpr float kC2 = 0.0009f;

typedef decltype(__builtin_amdgcn_cvt_pkrtz(0.f, 0.f)) half2v;

__device__ __forceinline__ float sgpr_f(float v) {
    return __int_as_float(__builtin_amdgcn_readfirstlane(__float_as_int(v)));
}
__device__ __forceinline__ int bci(half2v h) { return __builtin_bit_cast(int, h); }
__device__ __forceinline__ half2v bch(int i) { return __builtin_bit_cast(half2v, i); }

// static scatter ranges: output row oo = 4G-10+idx must lie in [0, 31]
#define A_LO(G) ((10 - 4*(G)) > 0 ? (10 - 4*(G)) : 0)
#define A_HI(G) ((41 - 4*(G)) < 11 ? (41 - 4*(G)) : 11)
#define B_LO(G) ((10 - 4*(G)) > 2 ? (10 - 4*(G)) : 2)
#define B_HI(G) ((41 - 4*(G)) < 13 ? (41 - 4*(G)) : 13)

__global__ __launch_bounds__(NT, 2) void ssim_wavetile(
    const float* __restrict__ logits,
    const float* __restrict__ gts,
    const float* __restrict__ window,
    float* __restrict__ partial)
{
    // [wid][buf][arr][idx]; arr: 0=evenA 1=oddA 2=evenB 3=oddB
    // A = {p01,p23,g01,g23}, B = {s01,s23,c01,c23}
    // entry m of parity q <-> col c0 + 2*(m-3) + q
    __shared__ uint4 S[4][2][4][72];   // 36 KB

    const int t    = threadIdx.x;
    const int lane = t & 63;
    const int wid  = t >> 6;

    // 1D taps = row sums of 2D window (sum(g)=1); SGPR-hoisted.
    float w[KW];
#pragma unroll
    for (int k = 0; k < KW; ++k) {
        float s = 0.f;
#pragma unroll
        for (int j = 0; j < KW; ++j) s += window[k * KW + j];
        w[k] = sgpr_f(s);
    }

    // f16 tap pairs (wk,wk), SGPR ints.
    int wk2i[KW];
#pragma unroll
    for (int k = 0; k < KW; ++k)
        wk2i[k] = __builtin_amdgcn_readfirstlane(
            bci(__builtin_amdgcn_cvt_pkrtz(w[k], w[k])));

    // f16 weight pairs for the vertical scatter (FULL guards - R12 lesson)
    int wpAi[12], wpBi[12];
#pragma unroll
    for (int p = 0; p < 12; ++p) {
        const float a0 = (10 - p >= 0 && 10 - p <= 10) ? w[10 - p] : 0.f;
        const float a1 = (11 - p >= 0 && 11 - p <= 10) ? w[11 - p] : 0.f;
        wpAi[p] = __builtin_amdgcn_readfirstlane(
            bci(__builtin_amdgcn_cvt_pkrtz(a0, a1)));
        const int q = p + 2;
        const float b0 = (12 - q >= 0 && 12 - q <= 10) ? w[12 - q] : 0.f;
        const float b1 = (13 - q >= 0 && 13 - q <= 10) ? w[13 - q] : 0.f;
        wpBi[p] = __builtin_amdgcn_readfirstlane(
            bci(__builtin_amdgcn_cvt_pkrtz(b0, b1)));
    }

    const int img = blockIdx.x >> 4;
    const int ty  = blockIdx.x & 15;
    const int y0  = ty * STRIP;
    const int c0  = wid << 7;             // wave's first output col
    const float* __restrict__ L = logits + (size_t)img * (H * W);
    const float* __restrict__ G = gts    + (size_t)img * (H * W);

    const int xe = c0 + 2 * lane;         // own even col (always in-image)

    // halo assignment: lanes 0-4 left (r=-5..-1), lanes 59-63 right (128..132)
    const bool hact = (lane < 5) || (lane >= 59);
    const int r    = (lane < 5) ? (lane - 5) : (128 + lane - 59);
    const int hpar = r & 1;
    const int hidx = ((r - hpar) / 2) + 3;          // 0..2 / 67..69
    const int ch_raw = c0 + r;
    const int ch   = min(max(ch_raw, 0), W - 1);
    const float mkh = (ch_raw == ch) ? 1.f : 0.f;

    // 16-slot rings, 4 fields x 2 output columns (statically indexed)
    float Pe1[16], Pe2[16], PeS[16], PeC[16];
    float Po1[16], Po2[16], PoS[16], PoC[16];
#pragma unroll
    for (int i = 0; i < 16; ++i) {
        Pe1[i] = 0.f; Pe2[i] = 0.f; PeS[i] = 0.f; PeC[i] = 0.f;
        Po1[i] = 0.f; Po2[i] = 0.f; PoS[i] = 0.f; PoC[i] = 0.f;
    }

    float ple[4], pge[4], plo[4], pgo[4], hl[4], hg[4];
#define PF(j, rr_expr)                                                         \
    {                                                                          \
        const int row  = y0 - HALF + (rr_expr);                                \
        const int rowc = min(max(row, 0), H - 1);                              \
        const float mk = (row == rowc) ? 1.f : 0.f;                            \
        const float2 lv = *(const float2*)(L + (size_t)rowc * W + xe);         \
        const float2 gv = *(const float2*)(G + (size_t)rowc * W + xe);         \
        ple[j] = mk * __builtin_amdgcn_rcpf(1.f + __expf(-lv.x));              \
        plo[j] = mk * __builtin_amdgcn_rcpf(1.f + __expf(-lv.y));              \
        pge[j] = mk * gv.x;                                                    \
        pgo[j] = mk * gv.y;                                                    \
        if (hact) {                                                            \
            const float hlv = L[(size_t)rowc * W + ch];                        \
            const float hgv = G[(size_t)rowc * W + ch];                        \
            hl[j] = (mk * mkh) * __builtin_amdgcn_rcpf(1.f + __expf(-hlv));    \
            hg[j] = (mk * mkh) * hgv;                                          \
        }                                                                      \
    }
#pragma unroll
    for (int j = 0; j < 4; ++j) PF(j, j)

    float acc = 0.f;

#define PACK_STAGE(BB, AARR, BARR, IDX, PLX, PGX)                              \
    {                                                                          \
        const float s0 = PLX[0]*PLX[0] + PGX[0]*PGX[0];                        \
        const float s1 = PLX[1]*PLX[1] + PGX[1]*PGX[1];                        \
        const float s2 = PLX[2]*PLX[2] + PGX[2]*PGX[2];                        \
        const float s3 = PLX[3]*PLX[3] + PGX[3]*PGX[3];                        \
        const float c0_ = PLX[0]*PGX[0], c1_ = PLX[1]*PGX[1];                  \
        const float c2_ = PLX[2]*PGX[2], c3_ = PLX[3]*PGX[3];                  \
        uint4 qa, qb;                                                          \
        qa.x = (unsigned)bci(__builtin_amdgcn_cvt_pkrtz(PLX[0], PLX[1]));      \
        qa.y = (unsigned)bci(__builtin_amdgcn_cvt_pkrtz(PLX[2], PLX[3]));      \
        qa.z = (unsigned)bci(__builtin_amdgcn_cvt_pkrtz(PGX[0], PGX[1]));      \
        qa.w = (unsigned)bci(__builtin_amdgcn_cvt_pkrtz(PGX[2], PGX[3]));      \
        qb.x = (unsigned)bci(__builtin_amdgcn_cvt_pkrtz(s0, s1));              \
        qb.y = (unsigned)bci(__builtin_amdgcn_cvt_pkrtz(s2, s3));              \
        qb.z = (unsigned)bci(__builtin_amdgcn_cvt_pkrtz(c0_, c1_));            \
        qb.w = (unsigned)bci(__builtin_amdgcn_cvt_pkrtz(c2_, c3_));            \
        S[wid][BB][AARR][IDX] = qa;                                            \
        S[wid][BB][BARR][IDX] = qb;                                            \
    }

#define FMA8(H1A,H1B,H2A,H2B,HSA,HSB,HCA,HCB, QA, QB, WW)                      \
        H1A += (WW) * bch((int)(QA).x);  H1B += (WW) * bch((int)(QA).y);       \
        H2A += (WW) * bch((int)(QA).z);  H2B += (WW) * bch((int)(QA).w);       \
        HSA += (WW) * bch((int)(QB).x);  HSB += (WW) * bch((int)(QB).y);       \
        HCA += (WW) * bch((int)(QB).z);  HCB += (WW) * bch((int)(QB).w);

#define SSIM_GROUP(GG)                                                         \
    {                                                                          \
        PACK_STAGE((GG) & 1, 0, 2, lane + 3, ple, pge)                         \
        PACK_STAGE((GG) & 1, 1, 3, lane + 3, plo, pgo)                         \
        if (hact) PACK_STAGE((GG) & 1, hpar, 2 + hpar, hidx, hl, hg)           \
        if ((GG) < 9) {                                                        \
            _Pragma("unroll")                                                  \
            for (int j = 0; j < 4; ++j) PF(j, 4 * ((GG) + 1) + j)              \
        } else if ((GG) == 9) {                                                \
            PF(0, 40)                                                          \
            PF(1, 41)                                                          \
            ple[2] = 0.f; ple[3] = 0.f; pge[2] = 0.f; pge[3] = 0.f;            \
            plo[2] = 0.f; plo[3] = 0.f; pgo[2] = 0.f; pgo[3] = 0.f;            \
            hl[2] = 0.f; hl[3] = 0.f; hg[2] = 0.f; hg[3] = 0.f;                \
        }                                                                      \
        asm volatile("s_waitcnt lgkmcnt(0)" ::: "memory");                     \
        __builtin_amdgcn_sched_barrier(0);                                     \
        const half2v hz = bch(0);                                              \
        half2v e1a = hz, e1b = hz, e2a = hz, e2b = hz;                         \
        half2v eSa = hz, eSb = hz, eCa = hz, eCb = hz;                         \
        half2v o1a = hz, o1b = hz, o2a = hz, o2b = hz;                         \
        half2v oSa = hz, oSb = hz, oCa = hz, oCb = hz;                         \
        _Pragma("unroll")                                                      \
        for (int i = 0; i < 6; ++i) { /* odd-parity entries o[lane+i] */       \
            const uint4 qo = S[wid][(GG) & 1][1][lane + i];                    \
            const uint4 ro = S[wid][(GG) & 1][3][lane + i];                    \
            const half2v we = bch(wk2i[2 * i]);   /* even out, d=2i */         \
            FMA8(e1a,e1b,e2a,e2b,eSa,eSb,eCa,eCb, qo, ro, we)                  \
            if (i >= 1) {                         /* odd out, d=2i-1 */        \
                const half2v wo = bch(wk2i[2 * i - 1]);                        \
                FMA8(o1a,o1b,o2a,o2b,oSa,oSb,oCa,oCb, qo, ro, wo)              \
            }                                                                  \
        }                                                                      \
        _Pragma("unroll")                                                      \
        for (int i = 0; i < 6; ++i) { /* even-parity entries e[lane+1+i] */    \
            const uint4 qe = S[wid][(GG) & 1][0][lane + 1 + i];                \
            const uint4 re = S[wid][(GG) & 1][2][lane + 1 + i];                \
            const half2v wo = bch(wk2i[2 * i]);   /* odd out, d=2i */          \
            FMA8(o1a,o1b,o2a,o2b,oSa,oSb,oCa,oCb, qe, re, wo)                  \
            if (i <= 4) {                         /* even out, d=2i+1 */       \
                const half2v we2 = bch(wk2i[2 * i + 1]);                       \
                FMA8(e1a,e1b,e2a,e2b,eSa,eSb,eCa,eCb, qe, re, we2)             \
            }                                                                  \
        }                                                                      \
        _Pragma("unroll")                                                      \
        for (int d = 0; d < 12; ++d) { /* rows (4G,4G+1), pruned static */     \
            if (d >= A_LO(GG) && d <= A_HI(GG)) {                              \
                const int s = (4 * (GG) + 6 + d) & 15;                         \
                const half2v wa = bch(wpAi[d]);                                \
                Pe1[s] = __builtin_amdgcn_fdot2(e1a, wa, Pe1[s], false);       \
                Pe2[s] = __builtin_amdgcn_fdot2(e2a, wa, Pe2[s], false);       \
                PeS[s] = __builtin_amdgcn_fdot2(eSa, wa, PeS[s], false);       \
                PeC[s] = __builtin_amdgcn_fdot2(eCa, wa, PeC[s], false);       \
                Po1[s] = __builtin_amdgcn_fdot2(o1a, wa, Po1[s], false);       \
                Po2[s] = __builtin_amdgcn_fdot2(o2a, wa, Po2[s], false);       \
                PoS[s] = __builtin_amdgcn_fdot2(oSa, wa, PoS[s], false);       \
                PoC[s] = __builtin_amdgcn_fdot2(oCa, wa, PoC[s], false);       \
            }                                                                  \
        }                                                                      \
        _Pragma("unroll")                                                      \
        for (int p = 2; p < 14; ++p) { /* rows (4G+2,4G+3), pruned static */   \
            if (p >= B_LO(GG) && p <= B_HI(GG)) {                              \
                const int s = (4 * (GG) + 6 + p) & 15;                         \
                const half2v wb2 = bch(wpBi[p - 2]);                           \
                Pe1[s] = __builtin_amdgcn_fdot2(e1b, wb2, Pe1[s], false);      \
                Pe2[s] = __builtin_amdgcn_fdot2(e2b, wb2, Pe2[s], false);      \
                PeS[s] = __builtin_amdgcn_fdot2(eSb, wb2, PeS[s], false);      \
                PeC[s] = __builtin_amdgcn_fdot2(eCb, wb2, PeC[s], false);      \
                Po1[s] = __builtin_amdgcn_fdot2(o1b, wb2, Po1[s], false);      \
                Po2[s] = __builtin_amdgcn_fdot2(o2b, wb2, Po2[s], false);      \
                PoS[s] = __builtin_amdgcn_fdot2(oSb, wb2, PoS[s], false);      \
                PoC[s] = __builtin_amdgcn_fdot2(oCb, wb2, PoC[s], false);      \
            }                                                                  \
        }                                                                      \
        _Pragma("unroll")                                                      \
        for (int p = 0; p < 4; ++p) { /* emit rows 4G-10+p, static guard */    \
            const int oo = 4 * (GG) - 10 + p;                                  \
            if (oo >= 0 && oo < STRIP) {                                       \
                const int s = oo & 15;                                         \
                {                                                              \
                    const float m1 = Pe1[s], m2 = Pe2[s];                      \
                    const float mu11 = m1*m1, mu22 = m2*m2, mu12 = m1*m2;      \
                    const float s12 = PeC[s] - mu12;                           \
                    const float sAB = PeS[s] - mu11 - mu22;                    \
                    const float num = (2.f*mu12 + kC1) * (2.f*s12 + kC2);      \
                    const float den = (mu11 + mu22 + kC1) * (sAB + kC2);       \
                    acc += num * __builtin_amdgcn_rcpf(den);                   \
                    Pe1[s] = 0.f; Pe2[s] = 0.f; PeS[s] = 0.f; PeC[s] = 0.f;    \
                }                                                              \
                {                                                              \
                    const float m1 = Po1[s], m2 = Po2[s];                      \
                    const float mu11 = m1*m1, mu22 = m2*m2, mu12 = m1*m2;      \
                    const float s12 = PoC[s] - mu12;                           \
                    const float sAB = PoS[s] - mu11 - mu22;                    \
                    const float num = (2.f*mu12 + kC1) * (2.f*s12 + kC2);      \
                    const float den = (mu11 + mu22 + kC1) * (sAB + kC2);       \
                    acc += num * __builtin_amdgcn_rcpf(den);                   \
                    Po1[s] = 0.f; Po2[s] = 0.f; PoS[s] = 0.f; PoC[s] = 0.f;    \
                }                                                              \
            }                                                                  \
        }                                                                      \
    }

    SSIM_GROUP(0)
    SSIM_GROUP(1)
    SSIM_GROUP(2)
    SSIM_GROUP(3)
    SSIM_GROUP(4)
    SSIM_GROUP(5)
    SSIM_GROUP(6)
    SSIM_GROUP(7)
    SSIM_GROUP(8)
    SSIM_GROUP(9)
    SSIM_GROUP(10)

#undef SSIM_GROUP
#undef FMA8
#undef PACK_STAGE
#undef PF

    // ---- per-wave reduction; no block barrier anywhere ----
#pragma unroll
    for (int off = 32; off > 0; off >>= 1) acc += __shfl_xor(acc, off);
    if (lane == 0) partial[(blockIdx.x << 2) + wid] = acc;
}

__global__ __launch_bounds__(256) void ssim_finalize(
    const float* __restrict__ partial, int nparts, double inv_count,
    float* __restrict__ out)
{
    __shared__ double sd[256];
    const int tid = threadIdx.x;
    double s = 0.0;
    for (int i = tid; i < nparts; i += 256) s += (double)partial[i];
    sd[tid] = s;
    __syncthreads();
    for (int st = 128; st > 0; st >>= 1) {
        if (tid < st) sd[tid] += sd[tid + st];
        __syncthreads();
    }
    if (tid == 0) out[0] = (float)(1.0 - sd[0] * inv_count);
}

extern "C" void kernel_launch(void* const* d_in, const int* in_sizes, int n_in,
                              void* d_out, int out_size, void* d_ws, size_t ws_size,
                              hipStream_t stream) {
    const float* logits = (const float*)d_in[0];
    const float* gts    = (const float*)d_in[1];
    const float* window = (const float*)d_in[2];
    float* out = (float*)d_out;

    const int nimg = in_sizes[0] / (H * W);   // 32
    const int nblocks = nimg * (H / STRIP);   // 512 (4 wave-tiles each)

    float* partial = (float*)d_ws;            // 2048 floats

    ssim_wavetile<<<nblocks, NT, 0, stream>>>(logits, gts, window, partial);

    const double inv_count = 1.0 / ((double)nimg * H * W);
    ssim_finalize<<<1, 256, 0, stream>>>(partial, nblocks * 4, inv_count, out);
}

// Round 22
// 36.292 us; speedup vs baseline: 6.6613x; 6.6613x over previous
//
#include <hip/hip_runtime.h>
#include <math.h>

// SSIM loss. R22: R20 (column-pairing, 36.2us best) + DEFERRED-SCATTER
// software pipeline. Hold group G's 16 h-fragments in regs across the
// barrier; after barrier G+1, the ~300 independent scatter/emit VALU ops of
// group G overlap group G+1's 24 ds_read_b128 latency (R20 accounting:
// VALU 7.3us + LDS 12us vs 36us measured -> ~17us exposed latency at
// 2 waves/SIMD; post-barrier code previously depended entirely on the
// just-issued reads).
//  - 4 fields {p,g,s=p^2+g^2,c=p*g} f16-packed, parity-split entries
//  - thread owns cols 2t,2t+1: 24 b128 reads / 2 outputs
//  - fully-static group instantiation; scatter ranges of G-1 constant-fold
//    (G=0's scatter statically empty; tail scatter after G=10)
// Spill ledger (R4/R5/R13/R21): ONE prefetch path, static indices, (256,2)
// budget. Falsified: barrier-drain(R15), blocks(R8/R17), super-groups(R18),
// wave-private dual-path(R14/R21).

#define KW 11
#define HALF 5
#define STRIP 32
#define W 512
#define H 512
#define NT 256
#define NE 264               // e/o array length (halo idx 0..2, 259..261)

static constexpr float kC1 = 0.0001f;
static constexpr float kC2 = 0.0009f;

typedef decltype(__builtin_amdgcn_cvt_pkrtz(0.f, 0.f)) half2v;

__device__ __forceinline__ float sgpr_f(float v) {
    return __int_as_float(__builtin_amdgcn_readfirstlane(__float_as_int(v)));
}
__device__ __forceinline__ int bci(half2v h) { return __builtin_bit_cast(int, h); }
__device__ __forceinline__ half2v bch(int i) { return __builtin_bit_cast(half2v, i); }

// static scatter ranges: output row oo = 4G-10+idx must lie in [0, 31]
#define A_LO(G) ((10 - 4*(G)) > 0 ? (10 - 4*(G)) : 0)
#define A_HI(G) ((41 - 4*(G)) < 11 ? (41 - 4*(G)) : 11)
#define B_LO(G) ((10 - 4*(G)) > 2 ? (10 - 4*(G)) : 2)
#define B_HI(G) ((41 - 4*(G)) < 13 ? (41 - 4*(G)) : 13)

__global__ __launch_bounds__(NT, 2) void ssim_strip(
    const float* __restrict__ logits,
    const float* __restrict__ gts,
    const float* __restrict__ window,
    float* __restrict__ partial)
{
    __shared__ uint4 eA[2][NE], oA[2][NE], eB[2][NE], oB[2][NE];
    __shared__ float red[NT / 64];

    const int t = threadIdx.x;

    // 1D taps = row sums of 2D window (sum(g)=1); SGPR-hoisted.
    float w[KW];
#pragma unroll
    for (int k = 0; k < KW; ++k) {
        float s = 0.f;
#pragma unroll
        for (int j = 0; j < KW; ++j) s += window[k * KW + j];
        w[k] = sgpr_f(s);
    }

    // f16 tap pairs (wk,wk), SGPR ints.
    int wk2i[KW];
#pragma unroll
    for (int k = 0; k < KW; ++k)
        wk2i[k] = __builtin_amdgcn_readfirstlane(
            bci(__builtin_amdgcn_cvt_pkrtz(w[k], w[k])));

    // f16 weight pairs for the vertical scatter (FULL guards - R12 lesson)
    int wpAi[12], wpBi[12];
#pragma unroll
    for (int p = 0; p < 12; ++p) {
        const float a0 = (10 - p >= 0 && 10 - p <= 10) ? w[10 - p] : 0.f;
        const float a1 = (11 - p >= 0 && 11 - p <= 10) ? w[11 - p] : 0.f;
        wpAi[p] = __builtin_amdgcn_readfirstlane(
            bci(__builtin_amdgcn_cvt_pkrtz(a0, a1)));
        const int q = p + 2;
        const float b0 = (12 - q >= 0 && 12 - q <= 10) ? w[12 - q] : 0.f;
        const float b1 = (13 - q >= 0 && 13 - q <= 10) ? w[13 - q] : 0.f;
        wpBi[p] = __builtin_amdgcn_readfirstlane(
            bci(__builtin_amdgcn_cvt_pkrtz(b0, b1)));
    }

    const int img = blockIdx.x >> 4;
    const int ty  = blockIdx.x & 15;
    const int y0  = ty * STRIP;
    const float* __restrict__ L = logits + (size_t)img * (H * W);
    const float* __restrict__ G = gts    + (size_t)img * (H * W);

    // zero halo entries once (indices 0..2 and 259..261), both buffers
    if (t < 6) {
        const int zi = (t < 3) ? t : (256 + t);   // 0,1,2,259,260,261
        const uint4 z = make_uint4(0, 0, 0, 0);
        eA[0][zi] = z; eA[1][zi] = z; oA[0][zi] = z; oA[1][zi] = z;
        eB[0][zi] = z; eB[1][zi] = z; oB[0][zi] = z; oB[1][zi] = z;
    }

    // 16-slot rings, 4 fields x 2 output columns (statically indexed)
    float Pe1[16], Pe2[16], PeS[16], PeC[16];
    float Po1[16], Po2[16], PoS[16], PoC[16];
#pragma unroll
    for (int i = 0; i < 16; ++i) {
        Pe1[i] = 0.f; Pe2[i] = 0.f; PeS[i] = 0.f; PeC[i] = 0.f;
        Po1[i] = 0.f; Po2[i] = 0.f; PoS[i] = 0.f; PoC[i] = 0.f;
    }

    // persistent h-fragments of the previous group (pipeline registers)
    const half2v HZ = bch(0);
    half2v He1a = HZ, He1b = HZ, He2a = HZ, He2b = HZ;
    half2v HeSa = HZ, HeSb = HZ, HeCa = HZ, HeCb = HZ;
    half2v Ho1a = HZ, Ho1b = HZ, Ho2a = HZ, Ho2b = HZ;
    half2v HoSa = HZ, HoSb = HZ, HoCa = HZ, HoCb = HZ;

    // prefetch: 4 rows x 2 cols (float2, cols adjacent)
    float ple[4], pge[4], plo[4], pgo[4];
#define PREFETCH_ROW(j, rr_expr)                                               \
    {                                                                          \
        const int row  = y0 - HALF + (rr_expr);                                \
        const int rowc = min(max(row, 0), H - 1);                              \
        const float mk = (row == rowc) ? 1.f : 0.f;                            \
        const float2 lv = *(const float2*)(L + (size_t)rowc * W + 2 * t);      \
        const float2 gv = *(const float2*)(G + (size_t)rowc * W + 2 * t);      \
        ple[j] = mk * __builtin_amdgcn_rcpf(1.f + __expf(-lv.x));              \
        plo[j] = mk * __builtin_amdgcn_rcpf(1.f + __expf(-lv.y));              \
        pge[j] = mk * gv.x;                                                    \
        pgo[j] = mk * gv.y;                                                    \
    }
#pragma unroll
    for (int j = 0; j < 4; ++j) PREFETCH_ROW(j, j)

    float acc = 0.f;

#define STAGE_PARITY(BB, PLX, PGX, EARR_A, EARR_B)                             \
    {                                                                          \
        const float s0 = PLX[0]*PLX[0] + PGX[0]*PGX[0];                        \
        const float s1 = PLX[1]*PLX[1] + PGX[1]*PGX[1];                        \
        const float s2 = PLX[2]*PLX[2] + PGX[2]*PGX[2];                        \
        const float s3 = PLX[3]*PLX[3] + PGX[3]*PGX[3];                        \
        const float c0 = PLX[0]*PGX[0], c1 = PLX[1]*PGX[1];                    \
        const float c2 = PLX[2]*PGX[2], c3 = PLX[3]*PGX[3];                    \
        uint4 qa, qb;                                                          \
        qa.x = (unsigned)bci(__builtin_amdgcn_cvt_pkrtz(PLX[0], PLX[1]));      \
        qa.y = (unsigned)bci(__builtin_amdgcn_cvt_pkrtz(PLX[2], PLX[3]));      \
        qa.z = (unsigned)bci(__builtin_amdgcn_cvt_pkrtz(PGX[0], PGX[1]));      \
        qa.w = (unsigned)bci(__builtin_amdgcn_cvt_pkrtz(PGX[2], PGX[3]));      \
        qb.x = (unsigned)bci(__builtin_amdgcn_cvt_pkrtz(s0, s1));              \
        qb.y = (unsigned)bci(__builtin_amdgcn_cvt_pkrtz(s2, s3));              \
        qb.z = (unsigned)bci(__builtin_amdgcn_cvt_pkrtz(c0, c1));              \
        qb.w = (unsigned)bci(__builtin_amdgcn_cvt_pkrtz(c2, c3));              \
        EARR_A[BB][t + 3] = qa;                                                \
        EARR_B[BB][t + 3] = qb;                                                \
    }

#define FMA8(H1A,H1B,H2A,H2B,HSA,HSB,HCA,HCB, QA, QB, WW)                      \
        H1A += (WW) * bch((int)(QA).x);  H1B += (WW) * bch((int)(QA).y);       \
        H2A += (WW) * bch((int)(QA).z);  H2B += (WW) * bch((int)(QA).w);       \
        HSA += (WW) * bch((int)(QB).x);  HSB += (WW) * bch((int)(QB).y);       \
        HCA += (WW) * bch((int)(QB).z);  HCB += (WW) * bch((int)(QB).w);

// scatter + emit for group G using the persistent H fragments (ranges fold;
// empty for G=-1)
#define SCATTER_EMIT(G)                                                        \
    {                                                                          \
        _Pragma("unroll")                                                      \
        for (int d = 0; d < 12; ++d) {                                         \
            if (d >= A_LO(G) && d <= A_HI(G)) {                                \
                const int s = (4 * (G) + 6 + d) & 15;                          \
                const half2v wa = bch(wpAi[d]);                                \
                Pe1[s] = __builtin_amdgcn_fdot2(He1a, wa, Pe1[s], false);      \
                Pe2[s] = __builtin_amdgcn_fdot2(He2a, wa, Pe2[s], false);      \
                PeS[s] = __builtin_amdgcn_fdot2(HeSa, wa, PeS[s], false);      \
                PeC[s] = __builtin_amdgcn_fdot2(HeCa, wa, PeC[s], false);      \
                Po1[s] = __builtin_amdgcn_fdot2(Ho1a, wa, Po1[s], false);      \
                Po2[s] = __builtin_amdgcn_fdot2(Ho2a, wa, Po2[s], false);      \
                PoS[s] = __builtin_amdgcn_fdot2(HoSa, wa, PoS[s], false);      \
                PoC[s] = __builtin_amdgcn_fdot2(HoCa, wa, PoC[s], false);      \
            }                                                                  \
        }                                                                      \
        _Pragma("unroll")                                                      \
        for (int p = 2; p < 14; ++p) {                                         \
            if (p >= B_LO(G) && p <= B_HI(G)) {                                \
                const int s = (4 * (G) + 6 + p) & 15;                          \
                const half2v wb2 = bch(wpBi[p - 2]);                           \
                Pe1[s] = __builtin_amdgcn_fdot2(He1b, wb2, Pe1[s], false);     \
                Pe2[s] = __builtin_amdgcn_fdot2(He2b, wb2, Pe2[s], false);     \
                PeS[s] = __builtin_amdgcn_fdot2(HeSb, wb2, PeS[s], false);     \
                PeC[s] = __builtin_amdgcn_fdot2(HeCb, wb2, PeC[s], false);     \
                Po1[s] = __builtin_amdgcn_fdot2(Ho1b, wb2, Po1[s], false);     \
                Po2[s] = __builtin_amdgcn_fdot2(Ho2b, wb2, Po2[s], false);     \
                PoS[s] = __builtin_amdgcn_fdot2(HoSb, wb2, PoS[s], false);     \
                PoC[s] = __builtin_amdgcn_fdot2(HoCb, wb2, PoC[s], false);     \
            }                                                                  \
        }                                                                      \
        _Pragma("unroll")                                                      \
        for (int p = 0; p < 4; ++p) {                                         \
            const int oo = 4 * (G) - 10 + p;                                   \
            if (oo >= 0 && oo < STRIP) {                                       \
                const int s = oo & 15;                                         \
                {                                                              \
                    const float m1 = Pe1[s], m2 = Pe2[s];                      \
                    const float mu11 = m1*m1, mu22 = m2*m2, mu12 = m1*m2;      \
                    const float s12 = PeC[s] - mu12;                           \
                    const float sAB = PeS[s] - mu11 - mu22;                    \
                    const float num = (2.f*mu12 + kC1) * (2.f*s12 + kC2);      \
                    const float den = (mu11 + mu22 + kC1) * (sAB + kC2);       \
                    acc += num * __builtin_amdgcn_rcpf(den);                   \
                    Pe1[s] = 0.f; Pe2[s] = 0.f; PeS[s] = 0.f; PeC[s] = 0.f;    \
                }                                                              \
                {                                                              \
                    const float m1 = Po1[s], m2 = Po2[s];                      \
                    const float mu11 = m1*m1, mu22 = m2*m2, mu12 = m1*m2;      \
                    const float s12 = PoC[s] - mu12;                           \
                    const float sAB = PoS[s] - mu11 - mu22;                    \
                    const float num = (2.f*mu12 + kC1) * (2.f*s12 + kC2);      \
                    const float den = (mu11 + mu22 + kC1) * (sAB + kC2);       \
                    acc += num * __builtin_amdgcn_rcpf(den);                   \
                    Po1[s] = 0.f; Po2[s] = 0.f; PoS[s] = 0.f; PoC[s] = 0.f;    \
                }                                                              \
            }                                                                  \
        }                                                                      \
    }

#define SSIM_GROUP(GG)                                                         \
    {                                                                          \
        STAGE_PARITY((GG) & 1, ple, pge, eA, eB)                               \
        STAGE_PARITY((GG) & 1, plo, pgo, oA, oB)                               \
        if ((GG) < 9) {                                                        \
            _Pragma("unroll")                                                  \
            for (int j = 0; j < 4; ++j) PREFETCH_ROW(j, 4 * ((GG) + 1) + j)    \
        } else if ((GG) == 9) {                                                \
            PREFETCH_ROW(0, 40)                                                \
            PREFETCH_ROW(1, 41)                                                \
            ple[2] = 0.f; ple[3] = 0.f; pge[2] = 0.f; pge[3] = 0.f;            \
            plo[2] = 0.f; plo[3] = 0.f; pgo[2] = 0.f; pgo[3] = 0.f;            \
        }                                                                      \
        asm volatile("s_waitcnt lgkmcnt(0)" ::: "memory");                     \
        __builtin_amdgcn_s_barrier();                                          \
        __builtin_amdgcn_sched_barrier(0);                                     \
        const half2v hz = bch(0);                                              \
        half2v e1a = hz, e1b = hz, e2a = hz, e2b = hz;                         \
        half2v eSa = hz, eSb = hz, eCa = hz, eCb = hz;                         \
        half2v o1a = hz, o1b = hz, o2a = hz, o2b = hz;                         \
        half2v oSa = hz, oSb = hz, oCa = hz, oCb = hz;                         \
        _Pragma("unroll")                                                      \
        for (int i = 0; i < 6; ++i) { /* odd-parity entries o[t+i] */          \
            const uint4 qo = oA[(GG) & 1][t + i];                              \
            const uint4 ro = oB[(GG) & 1][t + i];                              \
            const half2v we = bch(wk2i[2 * i]);   /* even out, d=2i */         \
            FMA8(e1a,e1b,e2a,e2b,eSa,eSb,eCa,eCb, qo, ro, we)                  \
            if (i >= 1) {                         /* odd out, d=2i-1 */        \
                const half2v wo = bch(wk2i[2 * i - 1]);                        \
                FMA8(o1a,o1b,o2a,o2b,oSa,oSb,oCa,oCb, qo, ro, wo)              \
            }                                                                  \
        }                                                                      \
        _Pragma("unroll")                                                      \
        for (int i = 0; i < 6; ++i) { /* even-parity entries e[t+1+i] */       \
            const uint4 qe = eA[(GG) & 1][t + 1 + i];                          \
            const uint4 re = eB[(GG) & 1][t + 1 + i];                          \
            const half2v wo = bch(wk2i[2 * i]);   /* odd out, d=2i */          \
            FMA8(o1a,o1b,o2a,o2b,oSa,oSb,oCa,oCb, qe, re, wo)                  \
            if (i <= 4) {                         /* even out, d=2i+1 */       \
                const half2v we2 = bch(wk2i[2 * i + 1]);                       \
                FMA8(e1a,e1b,e2a,e2b,eSa,eSb,eCa,eCb, qe, re, we2)             \
            }                                                                  \
        }                                                                      \
        /* scatter+emit of the PREVIOUS group: independent of this group's */  \
        /* ds_reads -> overlaps their latency (empty for GG=0) */              \
        SCATTER_EMIT((GG) - 1)                                                 \
        /* latch this group's h-fragments into the pipeline registers */       \
        He1a = e1a; He1b = e1b; He2a = e2a; He2b = e2b;                        \
        HeSa = eSa; HeSb = eSb; HeCa = eCa; HeCb = eCb;                        \
        Ho1a = o1a; Ho1b = o1b; Ho2a = o2a; Ho2b = o2b;                        \
        HoSa = oSa; HoSb = oSb; HoCa = oCa; HoCb = oCb;                        \
    }

    SSIM_GROUP(0)
    SSIM_GROUP(1)
    SSIM_GROUP(2)
    SSIM_GROUP(3)
    SSIM_GROUP(4)
    SSIM_GROUP(5)
    SSIM_GROUP(6)
    SSIM_GROUP(7)
    SSIM_GROUP(8)
    SSIM_GROUP(9)
    SSIM_GROUP(10)

    // pipeline drain: scatter+emit of group 10 (rows 30,31)
    SCATTER_EMIT(10)

#undef SSIM_GROUP
#undef SCATTER_EMIT
#undef FMA8
#undef STAGE_PARITY
#undef PREFETCH_ROW

    // ---- block reduction ----
#pragma unroll
    for (int off = 32; off > 0; off >>= 1) acc += __shfl_xor(acc, off);
    if ((t & 63) == 0) red[t >> 6] = acc;
    __syncthreads();
    if (t == 0) {
        float s = 0.f;
#pragma unroll
        for (int i = 0; i < NT / 64; ++i) s += red[i];
        partial[blockIdx.x] = s;
    }
}

__global__ __launch_bounds__(256) void ssim_finalize(
    const float* __restrict__ partial, int nparts, double inv_count,
    float* __restrict__ out)
{
    __shared__ double sd[256];
    const int tid = threadIdx.x;
    double s = 0.0;
    for (int i = tid; i < nparts; i += 256) s += (double)partial[i];
    sd[tid] = s;
    __syncthreads();
    for (int st = 128; st > 0; st >>= 1) {
        if (tid < st) sd[tid] += sd[tid + st];
        __syncthreads();
    }
    if (tid == 0) out[0] = (float)(1.0 - sd[0] * inv_count);
}

extern "C" void kernel_launch(void* const* d_in, const int* in_sizes, int n_in,
                              void* d_out, int out_size, void* d_ws, size_t ws_size,
                              hipStream_t stream) {
    const float* logits = (const float*)d_in[0];
    const float* gts    = (const float*)d_in[1];
    const float* window = (const float*)d_in[2];
    float* out = (float*)d_out;

    const int nimg = in_sizes[0] / (H * W);   // 32
    const int nblocks = nimg * (H / STRIP);   // 512

    float* partial = (float*)d_ws;

    ssim_strip<<<nblocks, NT, 0, stream>>>(logits, gts, window, partial);

    const double inv_count = 1.0 / ((double)nimg * H * W);
    ssim_finalize<<<1, 256, 0, stream>>>(partial, nblocks, inv_count, out);
}

// Round 23
// 35.423 us; speedup vs baseline: 6.8248x; 1.0245x over previous
//
#include <hip/hip_runtime.h>
#include <math.h>

// SSIM loss. R23: R20 (column pairing, 36.2us best) with LDS traffic halved
// AGAIN: stage ONLY {p,g} (one uint4/col); derive s=p^2+g^2 and c=p*g in
// registers per staged entry (8 pk-ops, shared across both output classes).
// 24 -> 12 ds_read_b128 per group, writes 4 -> 2, LDS 33.8 -> 16.9 KB.
// Rationale: only LDS-traffic cuts have moved duration since R16 (R20:
// -2.2us); VALU ~7us + LDS ~12us vs 36us measured. If this is neutral, the
// floor is the barrier-synced latency chain itself (decisive experiment).
//  - thread owns cols 2t,2t+1; parity-split entries; static weights
//  - 16-slot rings x 2 cols, fdot2 scatter pruned per group (R16)
//  - drain-free barrier; ONE prefetch path; static indices (spill ledger:
//    R4/R5/R13/R21 all spilled violating this)
// Falsified: barrier-drain(R15), blocks(R8/R17), super-groups(R18),
// wave-private(R14/R21), deferred-scatter pipeline(R22).

#define KW 11
#define HALF 5
#define STRIP 32
#define W 512
#define H 512
#define NT 256
#define NE 264               // e/o array length (halo idx 0..2, 259..261)

static constexpr float kC1 = 0.0001f;
static constexpr float kC2 = 0.0009f;

typedef decltype(__builtin_amdgcn_cvt_pkrtz(0.f, 0.f)) half2v;

__device__ __forceinline__ float sgpr_f(float v) {
    return __int_as_float(__builtin_amdgcn_readfirstlane(__float_as_int(v)));
}
__device__ __forceinline__ int bci(half2v h) { return __builtin_bit_cast(int, h); }
__device__ __forceinline__ half2v bch(int i) { return __builtin_bit_cast(half2v, i); }

// static scatter ranges: output row oo = 4G-10+idx must lie in [0, 31]
#define A_LO(G) ((10 - 4*(G)) > 0 ? (10 - 4*(G)) : 0)
#define A_HI(G) ((41 - 4*(G)) < 11 ? (41 - 4*(G)) : 11)
#define B_LO(G) ((10 - 4*(G)) > 2 ? (10 - 4*(G)) : 2)
#define B_HI(G) ((41 - 4*(G)) < 13 ? (41 - 4*(G)) : 13)

__global__ __launch_bounds__(NT, 2) void ssim_strip(
    const float* __restrict__ logits,
    const float* __restrict__ gts,
    const float* __restrict__ window,
    float* __restrict__ partial)
{
    // even cols in eA, odd in oA; col 2m -> e[m+3], col 2m+1 -> o[m+3]
    // entry = {p01,p23,g01,g23} f16-pair bits
    __shared__ uint4 eA[2][NE], oA[2][NE];
    __shared__ float red[NT / 64];

    const int t = threadIdx.x;

    // 1D taps = row sums of 2D window (sum(g)=1); SGPR-hoisted.
    float w[KW];
#pragma unroll
    for (int k = 0; k < KW; ++k) {
        float s = 0.f;
#pragma unroll
        for (int j = 0; j < KW; ++j) s += window[k * KW + j];
        w[k] = sgpr_f(s);
    }

    // f16 tap pairs (wk,wk), SGPR ints.
    int wk2i[KW];
#pragma unroll
    for (int k = 0; k < KW; ++k)
        wk2i[k] = __builtin_amdgcn_readfirstlane(
            bci(__builtin_amdgcn_cvt_pkrtz(w[k], w[k])));

    // f16 weight pairs for the vertical scatter (FULL guards - R12 lesson)
    int wpAi[12], wpBi[12];
#pragma unroll
    for (int p = 0; p < 12; ++p) {
        const float a0 = (10 - p >= 0 && 10 - p <= 10) ? w[10 - p] : 0.f;
        const float a1 = (11 - p >= 0 && 11 - p <= 10) ? w[11 - p] : 0.f;
        wpAi[p] = __builtin_amdgcn_readfirstlane(
            bci(__builtin_amdgcn_cvt_pkrtz(a0, a1)));
        const int q = p + 2;
        const float b0 = (12 - q >= 0 && 12 - q <= 10) ? w[12 - q] : 0.f;
        const float b1 = (13 - q >= 0 && 13 - q <= 10) ? w[13 - q] : 0.f;
        wpBi[p] = __builtin_amdgcn_readfirstlane(
            bci(__builtin_amdgcn_cvt_pkrtz(b0, b1)));
    }

    const int img = blockIdx.x >> 4;
    const int ty  = blockIdx.x & 15;
    const int y0  = ty * STRIP;
    const float* __restrict__ L = logits + (size_t)img * (H * W);
    const float* __restrict__ G = gts    + (size_t)img * (H * W);

    // zero halo entries once (indices 0..2 and 259..261), both buffers
    if (t < 6) {
        const int zi = (t < 3) ? t : (256 + t);   // 0,1,2,259,260,261
        const uint4 z = make_uint4(0, 0, 0, 0);
        eA[0][zi] = z; eA[1][zi] = z; oA[0][zi] = z; oA[1][zi] = z;
    }

    // 16-slot rings, 4 fields x 2 output columns (statically indexed)
    float Pe1[16], Pe2[16], PeS[16], PeC[16];
    float Po1[16], Po2[16], PoS[16], PoC[16];
#pragma unroll
    for (int i = 0; i < 16; ++i) {
        Pe1[i] = 0.f; Pe2[i] = 0.f; PeS[i] = 0.f; PeC[i] = 0.f;
        Po1[i] = 0.f; Po2[i] = 0.f; PoS[i] = 0.f; PoC[i] = 0.f;
    }

    // prefetch: 4 rows x 2 cols (float2, cols adjacent)
    float ple[4], pge[4], plo[4], pgo[4];
#define PREFETCH_ROW(j, rr_expr)                                               \
    {                                                                          \
        const int row  = y0 - HALF + (rr_expr);                                \
        const int rowc = min(max(row, 0), H - 1);                              \
        const float mk = (row == rowc) ? 1.f : 0.f;                            \
        const float2 lv = *(const float2*)(L + (size_t)rowc * W + 2 * t);      \
        const float2 gv = *(const float2*)(G + (size_t)rowc * W + 2 * t);      \
        ple[j] = mk * __builtin_amdgcn_rcpf(1.f + __expf(-lv.x));              \
        plo[j] = mk * __builtin_amdgcn_rcpf(1.f + __expf(-lv.y));              \
        pge[j] = mk * gv.x;                                                    \
        pgo[j] = mk * gv.y;                                                    \
    }
#pragma unroll
    for (int j = 0; j < 4; ++j) PREFETCH_ROW(j, j)

    float acc = 0.f;

#define STAGE_PARITY(BB, PLX, PGX, EARR_A)                                     \
    {                                                                          \
        uint4 qa;                                                              \
        qa.x = (unsigned)bci(__builtin_amdgcn_cvt_pkrtz(PLX[0], PLX[1]));      \
        qa.y = (unsigned)bci(__builtin_amdgcn_cvt_pkrtz(PLX[2], PLX[3]));      \
        qa.z = (unsigned)bci(__builtin_amdgcn_cvt_pkrtz(PGX[0], PGX[1]));      \
        qa.w = (unsigned)bci(__builtin_amdgcn_cvt_pkrtz(PGX[2], PGX[3]));      \
        EARR_A[BB][t + 3] = qa;                                                \
    }

// derive per-entry fields then FMA into one class (8 FMAs)
#define FMA8D(H1A,H1B,H2A,H2B,HSA,HSB,HCA,HCB, WW)                             \
        H1A += (WW) * p01;  H1B += (WW) * p23;                                 \
        H2A += (WW) * g01;  H2B += (WW) * g23;                                 \
        HSA += (WW) * s01;  HSB += (WW) * s23;                                 \
        HCA += (WW) * c01;  HCB += (WW) * c23;

#define SSIM_GROUP(GG)                                                         \
    {                                                                          \
        STAGE_PARITY((GG) & 1, ple, pge, eA)                                   \
        STAGE_PARITY((GG) & 1, plo, pgo, oA)                                   \
        if ((GG) < 9) {                                                        \
            _Pragma("unroll")                                                  \
            for (int j = 0; j < 4; ++j) PREFETCH_ROW(j, 4 * ((GG) + 1) + j)    \
        } else if ((GG) == 9) {                                                \
            PREFETCH_ROW(0, 40)                                                \
            PREFETCH_ROW(1, 41)                                                \
            ple[2] = 0.f; ple[3] = 0.f; pge[2] = 0.f; pge[3] = 0.f;            \
            plo[2] = 0.f; plo[3] = 0.f; pgo[2] = 0.f; pgo[3] = 0.f;            \
        }                                                                      \
        asm volatile("s_waitcnt lgkmcnt(0)" ::: "memory");                     \
        __builtin_amdgcn_s_barrier();                                          \
        __builtin_amdgcn_sched_barrier(0);                                     \
        const half2v hz = bch(0);                                              \
        half2v e1a = hz, e1b = hz, e2a = hz, e2b = hz;                         \
        half2v eSa = hz, eSb = hz, eCa = hz, eCb = hz;                         \
        half2v o1a = hz, o1b = hz, o2a = hz, o2b = hz;                         \
        half2v oSa = hz, oSb = hz, oCa = hz, oCb = hz;                         \
        _Pragma("unroll")                                                      \
        for (int i = 0; i < 6; ++i) { /* odd-parity entries o[t+i] */          \
            const uint4 qo = oA[(GG) & 1][t + i];                              \
            const half2v p01 = bch((int)qo.x), p23 = bch((int)qo.y);           \
            const half2v g01 = bch((int)qo.z), g23 = bch((int)qo.w);           \
            const half2v s01 = p01 * p01 + g01 * g01;                          \
            const half2v s23 = p23 * p23 + g23 * g23;                          \
            const half2v c01 = p01 * g01, c23 = p23 * g23;                     \
            const half2v we = bch(wk2i[2 * i]);   /* even out, d=2i */         \
            FMA8D(e1a,e1b,e2a,e2b,eSa,eSb,eCa,eCb, we)                         \
            if (i >= 1) {                         /* odd out, d=2i-1 */        \
                const half2v wo = bch(wk2i[2 * i - 1]);                        \
                FMA8D(o1a,o1b,o2a,o2b,oSa,oSb,oCa,oCb, wo)                     \
            }                                                                  \
        }                                                                      \
        _Pragma("unroll")                                                      \
        for (int i = 0; i < 6; ++i) { /* even-parity entries e[t+1+i] */       \
            const uint4 qe = eA[(GG) & 1][t + 1 + i];                          \
            const half2v p01 = bch((int)qe.x), p23 = bch((int)qe.y);           \
            const half2v g01 = bch((int)qe.z), g23 = bch((int)qe.w);           \
            const half2v s01 = p01 * p01 + g01 * g01;                          \
            const half2v s23 = p23 * p23 + g23 * g23;                          \
            const half2v c01 = p01 * g01, c23 = p23 * g23;                     \
            const half2v wo = bch(wk2i[2 * i]);   /* odd out, d=2i */          \
            FMA8D(o1a,o1b,o2a,o2b,oSa,oSb,oCa,oCb, wo)                         \
            if (i <= 4) {                         /* even out, d=2i+1 */       \
                const half2v we2 = bch(wk2i[2 * i + 1]);                       \
                FMA8D(e1a,e1b,e2a,e2b,eSa,eSb,eCa,eCb, we2)                    \
            }                                                                  \
        }                                                                      \
        _Pragma("unroll")                                                      \
        for (int d = 0; d < 12; ++d) { /* rows (4G,4G+1), pruned static */     \
            if (d >= A_LO(GG) && d <= A_HI(GG)) {                              \
                const int s = (4 * (GG) + 6 + d) & 15;                         \
                const half2v wa = bch(wpAi[d]);                                \
                Pe1[s] = __builtin_amdgcn_fdot2(e1a, wa, Pe1[s], false);       \
                Pe2[s] = __builtin_amdgcn_fdot2(e2a, wa, Pe2[s], false);       \
                PeS[s] = __builtin_amdgcn_fdot2(eSa, wa, PeS[s], false);       \
                PeC[s] = __builtin_amdgcn_fdot2(eCa, wa, PeC[s], false);       \
                Po1[s] = __builtin_amdgcn_fdot2(o1a, wa, Po1[s], false);       \
                Po2[s] = __builtin_amdgcn_fdot2(o2a, wa, Po2[s], false);       \
                PoS[s] = __builtin_amdgcn_fdot2(oSa, wa, PoS[s], false);       \
                PoC[s] = __builtin_amdgcn_fdot2(oCa, wa, PoC[s], false);       \
            }                                                                  \
        }                                                                      \
        _Pragma("unroll")                                                      \
        for (int p = 2; p < 14; ++p) { /* rows (4G+2,4G+3), pruned static */   \
            if (p >= B_LO(GG) && p <= B_HI(GG)) {                              \
                const int s = (4 * (GG) + 6 + p) & 15;                         \
                const half2v wb2 = bch(wpBi[p - 2]);                           \
                Pe1[s] = __builtin_amdgcn_fdot2(e1b, wb2, Pe1[s], false);      \
                Pe2[s] = __builtin_amdgcn_fdot2(e2b, wb2, Pe2[s], false);      \
                PeS[s] = __builtin_amdgcn_fdot2(eSb, wb2, PeS[s], false);      \
                PeC[s] = __builtin_amdgcn_fdot2(eCb, wb2, PeC[s], false);      \
                Po1[s] = __builtin_amdgcn_fdot2(o1b, wb2, Po1[s], false);      \
                Po2[s] = __builtin_amdgcn_fdot2(o2b, wb2, Po2[s], false);      \
                PoS[s] = __builtin_amdgcn_fdot2(oSb, wb2, PoS[s], false);      \
                PoC[s] = __builtin_amdgcn_fdot2(oCb, wb2, PoC[s], false);      \
            }                                                                  \
        }                                                                      \
        _Pragma("unroll")                                                      \
        for (int p = 0; p < 4; ++p) { /* emit rows 4G-10+p, static guard */    \
            const int oo = 4 * (GG) - 10 + p;                                  \
            if (oo >= 0 && oo < STRIP) {                                       \
                const int s = oo & 15;                                         \
                {                                                              \
                    const float m1 = Pe1[s], m2 = Pe2[s];                      \
                    const float mu11 = m1*m1, mu22 = m2*m2, mu12 = m1*m2;      \
                    const float s12 = PeC[s] - mu12;                           \
                    const float sAB = PeS[s] - mu11 - mu22;                    \
                    const float num = (2.f*mu12 + kC1) * (2.f*s12 + kC2);      \
                    const float den = (mu11 + mu22 + kC1) * (sAB + kC2);       \
                    acc += num * __builtin_amdgcn_rcpf(den);                   \
                    Pe1[s] = 0.f; Pe2[s] = 0.f; PeS[s] = 0.f; PeC[s] = 0.f;    \
                }                                                              \
                {                                                              \
                    const float m1 = Po1[s], m2 = Po2[s];                      \
                    const float mu11 = m1*m1, mu22 = m2*m2, mu12 = m1*m2;      \
                    const float s12 = PoC[s] - mu12;                           \
                    const float sAB = PoS[s] - mu11 - mu22;                    \
                    const float num = (2.f*mu12 + kC1) * (2.f*s12 + kC2);      \
                    const float den = (mu11 + mu22 + kC1) * (sAB + kC2);       \
                    acc += num * __builtin_amdgcn_rcpf(den);                   \
                    Po1[s] = 0.f; Po2[s] = 0.f; PoS[s] = 0.f; PoC[s] = 0.f;    \
                }                                                              \
            }                                                                  \
        }                                                                      \
    }

    SSIM_GROUP(0)
    SSIM_GROUP(1)
    SSIM_GROUP(2)
    SSIM_GROUP(3)
    SSIM_GROUP(4)
    SSIM_GROUP(5)
    SSIM_GROUP(6)
    SSIM_GROUP(7)
    SSIM_GROUP(8)
    SSIM_GROUP(9)
    SSIM_GROUP(10)

#undef SSIM_GROUP
#undef FMA8D
#undef STAGE_PARITY
#undef PREFETCH_ROW

    // ---- block reduction ----
#pragma unroll
    for (int off = 32; off > 0; off >>= 1) acc += __shfl_xor(acc, off);
    if ((t & 63) == 0) red[t >> 6] = acc;
    __syncthreads();
    if (t == 0) {
        float s = 0.f;
#pragma unroll
        for (int i = 0; i < NT / 64; ++i) s += red[i];
        partial[blockIdx.x] = s;
    }
}

__global__ __launch_bounds__(256) void ssim_finalize(
    const float* __restrict__ partial, int nparts, double inv_count,
    float* __restrict__ out)
{
    __shared__ double sd[256];
    const int tid = threadIdx.x;
    double s = 0.0;
    for (int i = tid; i < nparts; i += 256) s += (double)partial[i];
    sd[tid] = s;
    __syncthreads();
    for (int st = 128; st > 0; st >>= 1) {
        if (tid < st) sd[tid] += sd[tid + st];
        __syncthreads();
    }
    if (tid == 0) out[0] = (float)(1.0 - sd[0] * inv_count);
}

extern "C" void kernel_launch(void* const* d_in, const int* in_sizes, int n_in,
                              void* d_out, int out_size, void* d_ws, size_t ws_size,
                              hipStream_t stream) {
    const float* logits = (const float*)d_in[0];
    const float* gts    = (const float*)d_in[1];
    const float* window = (const float*)d_in[2];
    float* out = (float*)d_out;

    const int nimg = in_sizes[0] / (H * W);   // 32
    const int nblocks = nimg * (H / STRIP);   // 512

    float* partial = (float*)d_ws;

    ssim_strip<<<nblocks, NT, 0, stream>>>(logits, gts, window, partial);

    const double inv_count = 1.0 / ((double)nimg * H * W);
    ssim_finalize<<<1, 256, 0, stream>>>(partial, nblocks, inv_count, out);
}